// Round 12
// baseline (147.927 us; speedup 1.0000x reference)
//
#include <hip/hip_runtime.h>
#include <stdint.h>

#define M_TOTAL 32768   // B*T
#define NUMS    512
#define DIM     1024
#define TOPK    33

typedef __bf16 bf16_t;
typedef bf16_t bf16x8 __attribute__((ext_vector_type(8)));
typedef float  f32x4  __attribute__((ext_vector_type(4)));
typedef unsigned short ushort_t;

__device__ __forceinline__ ushort_t f2bf(float f) {
    union { float f; uint32_t u; } x; x.f = f;
    uint32_t r = x.u + 0x7FFFu + ((x.u >> 16) & 1u);
    return (ushort_t)(r >> 16);
}
__device__ __forceinline__ float bf2f(uint32_t u) {
    union { uint32_t u; float f; } x; x.u = u << 16;
    return x.f;
}

#define GLDS16(g, l) __builtin_amdgcn_global_load_lds( \
    (const __attribute__((address_space(1))) void*)(g), \
    (__attribute__((address_space(3))) void*)(l), 16, 0, 0)

// ---------------------------------------------------------------------------
// cvtprep: blocks 0..2047: data fp32 -> dataB bf16, XCD-aligned writes.
// blocks 2048..2559: mem fp32 -> memB bf16 + memT bf16 (transposed).
// ---------------------------------------------------------------------------
__global__ __launch_bounds__(256)
void cvtprep_kernel(const float* __restrict__ data, const float* __restrict__ mem,
                    ushort_t* __restrict__ dataB, ushort_t* __restrict__ memB,
                    ushort_t* __restrict__ memT) {
    __shared__ float tile[32][33];
    const int bid = blockIdx.x;
    const int t   = threadIdx.x;
    if (bid < 2048) {
        const int x = bid & 7;        // XCD
        const int j = bid >> 3;       // 0..255
        size_t i = ((size_t)x * 4096 + (size_t)j * 16) * DIM + t * 8;
#pragma unroll
        for (int it = 0; it < 8; ++it, i += 2048) {
            const float4 v0 = *(const float4*)(data + i);
            const float4 v1 = *(const float4*)(data + i + 4);
            union { ushort_t us[8]; uint4 v; } pk;
            pk.us[0] = f2bf(v0.x); pk.us[1] = f2bf(v0.y);
            pk.us[2] = f2bf(v0.z); pk.us[3] = f2bf(v0.w);
            pk.us[4] = f2bf(v1.x); pk.us[5] = f2bf(v1.y);
            pk.us[6] = f2bf(v1.z); pk.us[7] = f2bf(v1.w);
            *(uint4*)(dataB + i) = pk.v;
        }
    } else {
        const int pb = bid - 2048;
        const int bi = pb & 15;
        const int bj = pb >> 4;
        const int r  = t >> 3;
        const int c4 = (t & 7) * 4;
        const float4 v = *(const float4*)(mem + (size_t)(bi * 32 + r) * DIM + bj * 32 + c4);
        ushort4 b;
        b.x = f2bf(v.x); b.y = f2bf(v.y); b.z = f2bf(v.z); b.w = f2bf(v.w);
        *(ushort4*)(memB + (size_t)(bi * 32 + r) * DIM + bj * 32 + c4) = b;
        tile[r][c4 + 0] = v.x; tile[r][c4 + 1] = v.y;
        tile[r][c4 + 2] = v.z; tile[r][c4 + 3] = v.w;
        __syncthreads();
        ushort4 o;
        o.x = f2bf(tile[c4 + 0][r]); o.y = f2bf(tile[c4 + 1][r]);
        o.z = f2bf(tile[c4 + 2][r]); o.w = f2bf(tile[c4 + 3][r]);
        *(ushort4*)(memT + (size_t)(bj * 32 + r) * NUMS + bi * 32 + c4) = o;
    }
}

// ---------------------------------------------------------------------------
// G1: att = sigmoid(dataB @ memB^T / 32), 8-phase counted-vmcnt schedule.
// 256x256 tile, BK=64, 16 K-tiles, 512 thr = 8 waves (2M x 4N), wave tile
// 128x64 (m-frags 0-3 in A-half0, 4-7 in A-half1). B held in regs per K-tile.
// LDS 128KB: A[2dbuf][256r][128B] @0, B same @65536. Swizzle: slot s of row r
// holds chunk s^(r&7) (16B granule).
// Stage schedule (targets): ph1: Ah1(t+1); ph2: Bh0(t+2); ph3: Bh1(t+2);
// ph4: Ah0(t+2). Counted waits: vmcnt(10)@ph2 (verifies Ah1(t) for ph3),
// vmcnt(8)@ph4 (verifies Ah0/B of t+1 for next ph1). Tail: t=14 (8,2), t=15 (0,0).
// ---------------------------------------------------------------------------
__global__ __launch_bounds__(512, 2)
void g1_kernel(const ushort_t* __restrict__ dataB,
               const ushort_t* __restrict__ memB,
               ushort_t* __restrict__ att) {
    __shared__ __align__(16) unsigned char smem[131072];
    const int t    = threadIdx.x;
    const int lane = t & 63;
    const int wid  = t >> 6;        // 0..7
    const int wr   = wid >> 2;      // 0..1 (M)
    const int wc   = wid & 3;       // 0..3 (N)
    // XCD swizzle: 256 blocks, m-panel contiguous per XCD (matches cvtprep)
    const int wg = (blockIdx.x & 7) * 32 + (blockIdx.x >> 3);
    const int m0 = (wg >> 1) * 256;
    const int n0 = (wg & 1) * 256;

    f32x4 zero = {0.f, 0.f, 0.f, 0.f};
    f32x4 acc[8][4];
#pragma unroll
    for (int m = 0; m < 8; ++m)
#pragma unroll
        for (int n = 0; n < 4; ++n) acc[m][n] = zero;

    // staging lane map (per wave: 8 rows x 2 issues per half-tile)
    const int csrc = ((lane & 7) ^ (lane >> 3)) * 8;
    const ushort_t* aSrcW = dataB + (size_t)(m0 + wid * 8 + (lane >> 3)) * DIM + csrc;
    const ushort_t* bSrcW = memB  + (size_t)(n0 + wid * 8 + (lane >> 3)) * DIM + csrc;

    // fragment read bases
    const int slot0 = ((lane >> 4) ^ (lane & 7)) & 7;
    const int aRd = (wr * 64 + (lane & 15)) * 128 + slot0 * 16;
    const int bRd = (wc * 64 + (lane & 15)) * 128 + slot0 * 16;

#define STA(TK_, H_) {                                                          \
        const ushort_t* s_ = aSrcW + (size_t)((H_) * 128) * DIM + (TK_) * 64;   \
        unsigned char* d_ = smem + (((TK_) & 1) ? 32768 : 0) + (H_) * 16384     \
                          + wid * 1024 + lane * 16;                             \
        GLDS16(s_, d_); GLDS16(s_ + (size_t)64 * DIM, d_ + 8192); }
#define STB(TK_, H_) {                                                          \
        const ushort_t* s_ = bSrcW + (size_t)((H_) * 128) * DIM + (TK_) * 64;   \
        unsigned char* d_ = smem + 65536 + (((TK_) & 1) ? 32768 : 0)            \
                          + (H_) * 16384 + wid * 1024 + lane * 16;              \
        GLDS16(s_, d_); GLDS16(s_ + (size_t)64 * DIM, d_ + 8192); }
#define SBAR0 __builtin_amdgcn_sched_barrier(0);
#define G1_MM(MB_)                                                              \
    _Pragma("unroll") for (int i_ = 0; i_ < 2; ++i_)                            \
    _Pragma("unroll") for (int n_ = 0; n_ < 4; ++n_)                            \
    _Pragma("unroll") for (int k_ = 0; k_ < 2; ++k_)                            \
        acc[(MB_) + i_][n_] = __builtin_amdgcn_mfma_f32_16x16x32_bf16(          \
            Af[i_][k_], Bf[n_][k_], acc[(MB_) + i_][n_], 0, 0, 0);
#define RD_A(AO0_, AO1_)                                                        \
    Af[0][0] = *(const bf16x8*)(Ab + aRd + (AO0_));                             \
    Af[0][1] = *(const bf16x8*)(Ab + ((aRd + (AO0_)) ^ 64));                    \
    Af[1][0] = *(const bf16x8*)(Ab + aRd + (AO1_));                             \
    Af[1][1] = *(const bf16x8*)(Ab + ((aRd + (AO1_)) ^ 64));

#define G1_KT(T_, VM2_, VM4_, S1_, S2_, S3_, S4_) {                             \
    const unsigned char* Ab = smem + (((T_) & 1) ? 32768 : 0);                  \
    const unsigned char* Bb = smem + 65536 + (((T_) & 1) ? 32768 : 0);          \
    bf16x8 Af[2][2]; bf16x8 Bf[4][2];                                           \
    /* ---- phase 1: B all + A m0,m1 */                                         \
    _Pragma("unroll") for (int n_ = 0; n_ < 4; ++n_) {                          \
        Bf[n_][0] = *(const bf16x8*)(Bb + bRd + n_ * 2048);                     \
        Bf[n_][1] = *(const bf16x8*)(Bb + ((bRd + n_ * 2048) ^ 64));            \
    }                                                                           \
    RD_A(0, 2048)                                                               \
    if (S1_) STA((T_) + 1, 1)                                                   \
    __builtin_amdgcn_s_barrier();                                               \
    asm volatile("s_waitcnt lgkmcnt(0)" ::: "memory"); SBAR0                    \
    __builtin_amdgcn_s_setprio(1); G1_MM(0) __builtin_amdgcn_s_setprio(0);      \
    __builtin_amdgcn_s_barrier();                                               \
    /* ---- phase 2: A m2,m3 */                                                 \
    RD_A(4096, 6144)                                                            \
    if (S2_) STB((T_) + 2, 0)                                                   \
    asm volatile("s_waitcnt vmcnt(" #VM2_ ")" ::: "memory");                    \
    __builtin_amdgcn_s_barrier();                                               \
    asm volatile("s_waitcnt lgkmcnt(0)" ::: "memory"); SBAR0                    \
    __builtin_amdgcn_s_setprio(1); G1_MM(2) __builtin_amdgcn_s_setprio(0);      \
    __builtin_amdgcn_s_barrier();                                               \
    /* ---- phase 3: A m4,m5 (half1) */                                         \
    RD_A(16384, 18432)                                                          \
    if (S3_) STB((T_) + 2, 1)                                                   \
    __builtin_amdgcn_s_barrier();                                               \
    asm volatile("s_waitcnt lgkmcnt(0)" ::: "memory"); SBAR0                    \
    __builtin_amdgcn_s_setprio(1); G1_MM(4) __builtin_amdgcn_s_setprio(0);      \
    __builtin_amdgcn_s_barrier();                                               \
    /* ---- phase 4: A m6,m7 */                                                 \
    RD_A(20480, 22528)                                                          \
    if (S4_) STA((T_) + 2, 0)                                                   \
    asm volatile("s_waitcnt vmcnt(" #VM4_ ")" ::: "memory");                    \
    __builtin_amdgcn_s_barrier();                                               \
    asm volatile("s_waitcnt lgkmcnt(0)" ::: "memory"); SBAR0                    \
    __builtin_amdgcn_s_setprio(1); G1_MM(6) __builtin_amdgcn_s_setprio(0);      \
    __builtin_amdgcn_s_barrier(); }

    // ---- prologue: K0 full (Ah0,Ah1,Bh0,Bh1) + K1 (Bh0,Bh1,Ah0); order pinned
    STA(0, 0) SBAR0
    STA(0, 1) SBAR0
    STB(0, 0) SBAR0
    STB(0, 1) SBAR0
    STB(1, 0) SBAR0
    STB(1, 1) SBAR0
    STA(1, 0) SBAR0
    asm volatile("s_waitcnt vmcnt(6)" ::: "memory");
    __builtin_amdgcn_s_barrier();

    for (int tt = 0; tt < 14; ++tt) {
        G1_KT(tt, 10, 8, 1, 1, 1, 1)
    }
    G1_KT(14, 8, 2, 1, 0, 0, 0)
    G1_KT(15, 0, 0, 0, 0, 0, 0)
#undef G1_KT
#undef RD_A
#undef G1_MM
#undef STA
#undef STB

    // ---- epilogue: sigmoid -> bf16 att tile [256][256] in LDS, coalesced out
    ushort_t* lAtt = (ushort_t*)smem;
#pragma unroll
    for (int mi = 0; mi < 8; ++mi)
#pragma unroll
        for (int n = 0; n < 4; ++n)
#pragma unroll
            for (int reg = 0; reg < 4; ++reg) {
                const int row = (mi >> 2) * 128 + wr * 64 + (mi & 3) * 16
                              + (lane >> 4) * 4 + reg;
                const int col = wc * 64 + n * 16 + (lane & 15);
                const float x = acc[mi][n][reg] * 0.03125f;   // /sqrt(1024)
                const float s = 1.0f / (1.0f + __expf(-x));
                lAtt[row * 256 + col] = f2bf(s);
            }
    __syncthreads();
    {
        const uint4* lsrc = (const uint4*)lAtt;   // 8192 uint4, 32 per row
#pragma unroll
        for (int i = 0; i < 16; ++i) {
            const int idx = i * 512 + t;
            const int r   = idx >> 5;
            const int c16 = idx & 31;
            *(uint4*)(att + (size_t)(m0 + r) * 512 + n0 + c16 * 8) = lsrc[idx];
        }
    }
}

// ---------------------------------------------------------------------------
// topk: temporal[row] = mean of top-33 of att[row][:] via ballot radix-select.
// ---------------------------------------------------------------------------
__global__ __launch_bounds__(256, 8)
void topk_kernel(const ushort_t* __restrict__ att,
                 float* __restrict__ temporal) {
    const int t    = threadIdx.x;
    const int lane = t & 63;
    const int wid  = t >> 6;
    const int base = blockIdx.x * 16 + wid * 4;

    for (int ri = 0; ri < 4; ++ri) {
        const int row = base + ri;
        const uint4 rv = *(const uint4*)(att + (size_t)row * 512 + lane * 8);
        uint32_t u[8];
        u[0] = rv.x & 0xFFFFu; u[1] = rv.x >> 16;
        u[2] = rv.y & 0xFFFFu; u[3] = rv.y >> 16;
        u[4] = rv.z & 0xFFFFu; u[5] = rv.z >> 16;
        u[6] = rv.w & 0xFFFFu; u[7] = rv.w >> 16;
        uint32_t tc = 0;
#pragma unroll
        for (int b = 14; b >= 0; --b) {
            const uint32_t cand = tc | (1u << b);
            int c = 0;
#pragma unroll
            for (int j = 0; j < 8; ++j)
                c += __popcll(__ballot(u[j] >= cand));
            if (c >= TOPK) tc = cand;
        }
        float sgt = 0.f; int cgt = 0;
#pragma unroll
        for (int j = 0; j < 8; ++j) {
            if (u[j] > tc) { sgt += bf2f(u[j]); cgt++; }
        }
#pragma unroll
        for (int off = 32; off >= 1; off >>= 1) {
            sgt += __shfl_xor(sgt, off);
            cgt += __shfl_xor(cgt, off);
        }
        if (lane == 0)
            temporal[row] = (sgt + (float)(TOPK - cgt) * bf2f(tc)) * (1.0f / 33.0f);
    }
}

// ---------------------------------------------------------------------------
// G2: aug = att bf16 @ memT^T. m97-class single-buffer 32KB, 128x128, BK=64,
// 4 waves, XCD-swizzled. (unchanged)
// ---------------------------------------------------------------------------
__global__ __launch_bounds__(256, 4)
void g2_kernel(const ushort_t* __restrict__ att,
               const ushort_t* __restrict__ memT,
               float* __restrict__ aug) {
    __shared__ __align__(16) unsigned char smem[32768];
    const int t    = threadIdx.x;
    const int lane = t & 63;
    const int wid  = t >> 6;
    const int wr   = wid >> 1;
    const int wc   = wid & 1;
    const int wg = (blockIdx.x & 7) * 256 + (blockIdx.x >> 3);
    const int m0 = (wg >> 3) * 128;
    const int n0 = (wg & 7) * 128;

    f32x4 zero = {0.f, 0.f, 0.f, 0.f};
    f32x4 acc[4][4];
#pragma unroll
    for (int m = 0; m < 4; ++m)
#pragma unroll
        for (int n = 0; n < 4; ++n) acc[m][n] = zero;

    const int srcoff = (((lane & 7) ^ (lane >> 3)) & 7) * 8;
    const ushort_t* aS = att  + (size_t)(m0 + wid * 32 + (lane >> 3)) * 512 + srcoff;
    const ushort_t* bS = memT + (size_t)(n0 + wid * 32 + (lane >> 3)) * 512 + srcoff;

    for (int tt = 0; tt < 8; ++tt) {
        {
            unsigned char* da = smem + wid * 4096 + lane * 16;
            unsigned char* db = da + 16384;
            const ushort_t* sa = aS + tt * 64;
            const ushort_t* sb = bS + tt * 64;
            GLDS16(sa,            da);        GLDS16(sb,            db);
            GLDS16(sa +  8 * 512, da + 1024); GLDS16(sb +  8 * 512, db + 1024);
            GLDS16(sa + 16 * 512, da + 2048); GLDS16(sb + 16 * 512, db + 2048);
            GLDS16(sa + 24 * 512, da + 3072); GLDS16(sb + 24 * 512, db + 3072);
        }
        __syncthreads();
#pragma unroll
        for (int ki = 0; ki < 2; ++ki) {
            const int ch = ki * 4 + (lane >> 4);
            bf16x8 af[4], bfr[4];
#pragma unroll
            for (int m = 0; m < 4; ++m) {
                const int row = wr * 64 + m * 16 + (lane & 15);
                af[m] = *(const bf16x8*)(smem + row * 128 + ((ch ^ (row & 7)) << 4));
            }
#pragma unroll
            for (int n = 0; n < 4; ++n) {
                const int col = wc * 64 + n * 16 + (lane & 15);
                bfr[n] = *(const bf16x8*)(smem + 16384 + col * 128 + ((ch ^ (col & 7)) << 4));
            }
#pragma unroll
            for (int m = 0; m < 4; ++m)
#pragma unroll
                for (int n = 0; n < 4; ++n)
                    acc[m][n] = __builtin_amdgcn_mfma_f32_16x16x32_bf16(
                        af[m], bfr[n], acc[m][n], 0, 0, 0);
        }
        __syncthreads();
    }

#pragma unroll
    for (int m = 0; m < 4; ++m)
#pragma unroll
        for (int n = 0; n < 4; ++n)
#pragma unroll
            for (int reg = 0; reg < 4; ++reg) {
                const int row = m0 + wr * 64 + m * 16 + (lane >> 4) * 4 + reg;
                const int col = n0 + wc * 64 + n * 16 + (lane & 15);
                aug[(size_t)row * DIM + col] = acc[m][n][reg];
            }
}

// ---------------------------------------------------------------------------
extern "C" void kernel_launch(void* const* d_in, const int* in_sizes, int n_in,
                              void* d_out, int out_size, void* d_ws, size_t ws_size,
                              hipStream_t stream) {
    const float* data = (const float*)d_in[0];   // [16,2048,1024]
    const float* mem  = (const float*)d_in[1];   // [512,1024]
    float* temporal = (float*)d_out;             // [32768]
    float* aug      = (float*)d_out + M_TOTAL;   // [32768,1024] fp32 (128MB)

    ushort_t* memB = (ushort_t*)d_ws;                    // 1MB
    ushort_t* memT = memB + (size_t)NUMS * DIM;          // 1MB
    ushort_t* attw = memT + (size_t)DIM * NUMS;          // 32MB
    ushort_t* dataB = (ushort_t*)aug;                    // 64MB, consumed pre-g2

    cvtprep_kernel<<<2560, 256, 0, stream>>>(data, mem, dataB, memB, memT);
    g1_kernel<<<(M_TOTAL / 256) * (NUMS / 256), 512, 0, stream>>>(dataB, memB, attw);
    topk_kernel<<<M_TOTAL / 16, 256, 0, stream>>>(attw, temporal);
    g2_kernel<<<(M_TOTAL / 128) * (DIM / 128), 256, 0, stream>>>(attw, memT, aug);
}